// Round 10
// baseline (89.332 us; speedup 1.0000x reference)
//
#include <hip/hip_runtime.h>

#define MD   4
#define B_   4
#define C_   128
#define H_   128
#define W_   256
#define ND   9             // 2*MD+1 displacements per axis
#define NW   9             // waves per block, one per dy
#define XPT  8             // x pixels per lane; 32 lanes cover W, 2 rows/wave
#define CHK  16            // t1 channels staged per chunk
#define NCHK (C_ / CHK)    // 8 chunks

typedef float float4v __attribute__((ext_vector_type(4)));

// One block per (b, y-pair); 9 waves, one per dy; lanes 0-31 -> row y0,
// lanes 32-63 -> row y0+1 (R9 structure, validated).
// NEW: t1 is read through LDS. All 9 waves consumed the SAME t1 row pair
// per channel through L1 (9x redundancy = half of the 36KB/CU/ch L1 load
// that R4/R8/R9 all pinned at). t1 is now staged once per block in
// 16-channel double-buffered chunks via global_load_lds; L1 keeps only t2.
__global__ __launch_bounds__(NW * 64, 3)   // VGPR cap ~170; 1 block/CU
void corr_kernel(const float* __restrict__ t1,
                 const float* __restrict__ t2,
                 float* __restrict__ out) {
    __shared__ __align__(16) float t1s[2][CHK][2][W_];   // 65536 B

    const int tid  = threadIdx.x;
    const int lane = tid & 63;
    const int w    = tid >> 6;                 // wave id == dy
    const int bid  = blockIdx.x;               // 256 blocks = 8 XCD * 32
    const int swz  = (bid & 7) * 32 + (bid >> 3);
    const int yp   = swz & 63;                 // y-pair index 0..63
    const int b    = swz >> 6;                 // 0..3
    const int y0   = yp * 2;
    const int half = lane >> 5;                // 0: row y0, 1: row y0+1
    const int lx   = lane & 31;
    const int x0   = lx * XPT;                 // 0..248
    const int yrow = y0 + half;                // t1/out row
    const int yy   = yrow + w - MD;            // t2 row (may be OOB)
    const bool live = (0 <= yy) && (yy < H_);
    const int  yc  = yy < 0 ? 0 : (yy > H_ - 1 ? H_ - 1 : yy);
    const float sc = live ? (1.0f / (float)C_) : 0.0f;
    const bool lm  = (lx == 0);                // left halo is pad-zero
    const bool rm  = (lx == 31);               // right halo is pad-zero

    float acc[ND][XPT];
    #pragma unroll
    for (int dx = 0; dx < ND; ++dx)
        #pragma unroll
        for (int j = 0; j < XPT; ++j) acc[dx][j] = 0.0f;

    const float* p2 = t2 + (((size_t)(b * C_)) * H_ + yc) * W_ + x0;
    const size_t chstr = (size_t)H_ * W_;

    // stage chunk k (16 channels x 2 rows of t1) into buffer `buf`.
    // 32 slots of 1KB; wave w takes slots w, w+9, w+18, w+27.
    // dst is wave-uniform; HW scatters lane*16B -> fills the row linearly.
    auto STAGE = [&](int buf, int k) {
        const int c0 = k * CHK;
        for (int s = w; s < 2 * CHK; s += NW) {
            const int ch  = s >> 1;
            const int row = s & 1;
            const float* src =
                t1 + (((size_t)(b * C_ + c0 + ch)) * H_ + (y0 + row)) * W_ + lane * 4;
            __builtin_amdgcn_global_load_lds(
                (const __attribute__((address_space(1))) unsigned int*)src,
                (__attribute__((address_space(3))) unsigned int*)&t1s[buf][ch][row][0],
                16, 0, 0);
        }
    };

    STAGE(0, 0);
    __syncthreads();                            // chunk 0 landed

    for (int k = 0; k < NCHK; ++k) {
        const int buf = k & 1;
        if (k + 1 < NCHK) STAGE(buf ^ 1, k + 1);   // in flight during compute
        const int c0 = k * CHK;

        #pragma unroll 2
        for (int ch = 0; ch < CHK; ++ch) {
            // t1 from LDS (conflict-optimal stride-32B b128 reads)
            const float4v a0 = *(const float4v*)&t1s[buf][ch][half][x0];
            const float4v a1 = *(const float4v*)&t1s[buf][ch][half][x0 + 4];
            // t2 from global (L1/L2/L3)
            const float4v v0 = *(const float4v*)(p2 + (size_t)(c0 + ch) * chstr);
            const float4v v1 = *(const float4v*)(p2 + (size_t)(c0 + ch) * chstr + 4);

            // win[k] = t2 at x = x0 - 4 + k, k = 0..15
            float win[XPT + 2 * MD];
            #pragma unroll
            for (int q = 0; q < 4; ++q) {
                const float up = __shfl_up(v1[q], 1);    // lane-1's upper half
                const float dn = __shfl_down(v0[q], 1);  // lane+1's lower half
                win[q]      = lm ? 0.0f : up;
                win[4 + q]  = v0[q];
                win[8 + q]  = v1[q];
                win[12 + q] = rm ? 0.0f : dn;
            }

            #pragma unroll
            for (int dx = 0; dx < ND; ++dx)
                #pragma unroll
                for (int j = 0; j < XPT; ++j) {
                    const float aj = (j < 4) ? a0[j] : a1[j - 4];
                    acc[dx][j] = fmaf(aj, win[dx + j], acc[dx][j]);
                }
        }
        __syncthreads();   // staged k+1 landed; all waves done with buf
    }

    #pragma unroll
    for (int dx = 0; dx < ND; ++dx) {
        float4v o0, o1;
        #pragma unroll
        for (int j = 0; j < 4; ++j) {
            o0[j] = acc[dx][j]     * sc;
            o1[j] = acc[dx][4 + j] * sc;
        }
        const size_t oidx =
            (((size_t)(b * ND * ND) + w * ND + dx) * H_ + yrow) * W_ + x0;
        *(float4v*)&out[oidx]     = o0;
        *(float4v*)&out[oidx + 4] = o1;
    }
}

extern "C" void kernel_launch(void* const* d_in, const int* in_sizes, int n_in,
                              void* d_out, int out_size, void* d_ws, size_t ws_size,
                              hipStream_t stream) {
    const float* t1 = (const float*)d_in[0];
    const float* t2 = (const float*)d_in[1];
    float* out      = (float*)d_out;
    corr_kernel<<<dim3(B_ * H_ / 2), NW * 64, 0, stream>>>(t1, t2, out);
}

// Round 11
// 76.402 us; speedup vs baseline: 1.1692x; 1.1692x over previous
//
#include <hip/hip_runtime.h>

#define MD   4
#define B_   4
#define C_   128
#define H_   128
#define W_   256
#define ND   9            // 2*MD+1 displacements per axis
#define NW   9            // waves per block, one per dy
#define XPT  8            // x pixels per lane; 32 lanes cover W, 2 rows/wave

typedef float float4v __attribute__((ext_vector_type(4)));

// R9 skeleton (one block per (b,y-pair); 9 waves = 9 dy; lanes 0-31 row y0,
// lanes 32-63 row y0+1; XCD swizzle; clamped-row + zero-scale OOB handling)
// with the cross-lane shuffles ABLATED: each lane loads its full 16-float
// t2 window directly as 4 aligned float4s (x0-4, x0, x0+4, x0+8), edge
// lanes clamped + cndmask-zeroed. No LDS, no barriers, no DS ops at all.
__global__ __launch_bounds__(NW * 64, 3)   // VGPR cap ~170; 1 block/CU
void corr_kernel(const float* __restrict__ t1,
                 const float* __restrict__ t2,
                 float* __restrict__ out) {
    const int tid  = threadIdx.x;
    const int lane = tid & 63;
    const int w    = tid >> 6;                 // wave id == dy
    const int bid  = blockIdx.x;               // 256 blocks = 8 XCD * 32
    const int swz  = (bid & 7) * 32 + (bid >> 3);
    const int yp   = swz & 63;                 // y-pair index 0..63
    const int b    = swz >> 6;                 // 0..3
    const int y0   = yp * 2;
    const int half = lane >> 5;                // 0: row y0, 1: row y0+1
    const int lx   = lane & 31;
    const int x0   = lx * XPT;                 // 0..248
    const int yrow = y0 + half;                // t1/out row
    const int yy   = yrow + w - MD;            // t2 row (may be OOB)
    const bool live = (0 <= yy) && (yy < H_);
    const int  yc  = yy < 0 ? 0 : (yy > H_ - 1 ? H_ - 1 : yy);
    const float sc = live ? (1.0f / (float)C_) : 0.0f;
    const bool lm  = (lx == 0);                // left halo is pad-zero
    const bool rm  = (lx == 31);               // right halo is pad-zero
    const int offL = lm ? 0 : -4;              // clamped halo addresses
    const int offR = rm ? 0 :  8;

    float acc[ND][XPT];
    #pragma unroll
    for (int dx = 0; dx < ND; ++dx)
        #pragma unroll
        for (int j = 0; j < XPT; ++j) acc[dx][j] = 0.0f;

    const float* p1 = t1 + (((size_t)(b * C_)) * H_ + yrow) * W_ + x0;
    const float* p2 = t2 + (((size_t)(b * C_)) * H_ + yc  ) * W_ + x0;
    const size_t chstr = (size_t)H_ * W_;

    #pragma unroll 2
    for (int c = 0; c < C_; ++c) {
        const float* pc1 = p1 + (size_t)c * chstr;
        const float* pc2 = p2 + (size_t)c * chstr;
        const float4v a0 = *(const float4v*)(pc1);
        const float4v a1 = *(const float4v*)(pc1 + 4);

        // win[k] = t2 at x = x0 - 4 + k, k = 0..15, via 4 aligned b128
        float4v wl = *(const float4v*)(pc2 + offL);
        const float4v v0 = *(const float4v*)(pc2);
        const float4v v1 = *(const float4v*)(pc2 + 4);
        float4v wr = *(const float4v*)(pc2 + offR);
        #pragma unroll
        for (int q = 0; q < 4; ++q) {
            wl[q] = lm ? 0.0f : wl[q];
            wr[q] = rm ? 0.0f : wr[q];
        }

        float win[XPT + 2 * MD];
        #pragma unroll
        for (int q = 0; q < 4; ++q) {
            win[q]      = wl[q];
            win[4 + q]  = v0[q];
            win[8 + q]  = v1[q];
            win[12 + q] = wr[q];
        }

        #pragma unroll
        for (int dx = 0; dx < ND; ++dx)
            #pragma unroll
            for (int j = 0; j < XPT; ++j) {
                const float aj = (j < 4) ? a0[j] : a1[j - 4];
                acc[dx][j] = fmaf(aj, win[dx + j], acc[dx][j]);
            }
    }

    #pragma unroll
    for (int dx = 0; dx < ND; ++dx) {
        float4v o0, o1;
        #pragma unroll
        for (int j = 0; j < 4; ++j) {
            o0[j] = acc[dx][j]     * sc;
            o1[j] = acc[dx][4 + j] * sc;
        }
        const size_t oidx =
            (((size_t)(b * ND * ND) + w * ND + dx) * H_ + yrow) * W_ + x0;
        *(float4v*)&out[oidx]     = o0;
        *(float4v*)&out[oidx + 4] = o1;
    }
}

extern "C" void kernel_launch(void* const* d_in, const int* in_sizes, int n_in,
                              void* d_out, int out_size, void* d_ws, size_t ws_size,
                              hipStream_t stream) {
    const float* t1 = (const float*)d_in[0];
    const float* t2 = (const float*)d_in[1];
    float* out      = (float*)d_out;
    corr_kernel<<<dim3(B_ * H_ / 2), NW * 64, 0, stream>>>(t1, t2, out);
}

// Round 12
// 75.567 us; speedup vs baseline: 1.1822x; 1.0111x over previous
//
#include <hip/hip_runtime.h>

#define MD   4
#define B_   4
#define C_   128
#define H_   128
#define W_   256
#define ND   9             // 2*MD+1 displacements per axis
#define NW   9             // waves per block, one per dy
#define XPT  8             // x pixels per lane; 32 lanes cover W, 2 rows/wave
#define CHK  2             // channels staged per phase
#define NPH  (C_ / CHK)    // 64 phases
#define NROW 10            // t2 rows staged per channel (y0-4 .. y0+5)

typedef float float4v __attribute__((ext_vector_type(4)));

// R11 skeleton; t2 now staged in LDS (the actual miss stream), double-
// buffered 2-channel phases, stage-before-compute so the barrier vmcnt
// drain is covered by ~1100cy of FMAs. LDS rows XOR-swizzled at 16B-block
// granularity (phys = j ^ ((j>>3)&7)) via pre-swizzled gload_lds SOURCE +
// swizzled ds_read addresses (both-sides-or-neither rule).
__global__ __launch_bounds__(NW * 64, 3)   // VGPR cap ~170; 1 block/CU
void corr_kernel(const float* __restrict__ t1,
                 const float* __restrict__ t2,
                 float* __restrict__ out) {
    __shared__ __align__(16) float t2s[2][CHK][NROW][W_];   // 40960 B

    const int tid  = threadIdx.x;
    const int lane = tid & 63;
    const int w    = tid >> 6;                 // wave id == dy
    const int bid  = blockIdx.x;               // 256 blocks = 8 XCD * 32
    const int swz  = (bid & 7) * 32 + (bid >> 3);
    const int yp   = swz & 63;                 // y-pair index 0..63
    const int b    = swz >> 6;                 // 0..3
    const int y0   = yp * 2;
    const int half = lane >> 5;                // 0: row y0, 1: row y0+1
    const int lx   = lane & 31;
    const int x0   = lx * XPT;                 // 0..248
    const int yrow = y0 + half;                // t1/out row
    const int yy   = yrow + w - MD;            // t2 row (may be OOB)
    const bool live = (0 <= yy) && (yy < H_);
    const float sc = live ? (1.0f / (float)C_) : 0.0f;
    const bool lm  = (lx == 0);                // left halo is pad-zero
    const bool rm  = (lx == 31);               // right halo is pad-zero
    const int r_lds = w + half;                // staged-row index 0..9

    // window blocks (16B) within a 256-float row, clamped at edges
    const int j0 = lm ? 0  : 2 * lx - 1;
    const int j1 = 2 * lx;
    const int j2 = 2 * lx + 1;
    const int j3 = rm ? 63 : 2 * lx + 2;
    // XOR swizzle: physical byte offset of logical block j within a row
#define SWZB(j) ((((j) ^ (((j) >> 3) & 7)) << 4))
    const int o0 = SWZB(j0), o1 = SWZB(j1), o2 = SWZB(j2), o3 = SWZB(j3);
    // per-lane source block for staging (involution: fetch logical block
    // j = l ^ ((l>>3)&7) so it lands at physical block l)
    const int jsrc = lane ^ ((lane >> 3) & 7);

    float acc[ND][XPT];
    #pragma unroll
    for (int dx = 0; dx < ND; ++dx)
        #pragma unroll
        for (int j = 0; j < XPT; ++j) acc[dx][j] = 0.0f;

    const float* p1 = t1 + (((size_t)(b * C_)) * H_ + yrow) * W_ + x0;
    const size_t chstr = (size_t)H_ * W_;

    // stage CHK channels x NROW t2 rows of phase ph into buffer buf.
    // slots s = ch2*NROW + r (20); wave w covers s = w, w+9, w+18(<20).
    auto STAGE = [&](int buf, int ph) {
        const int c0 = ph * CHK;
        #pragma unroll
        for (int k = 0; k < 3; ++k) {
            const int s = w + k * NW;
            if (s < CHK * NROW) {              // wave-uniform guard
                const int ch2 = s / NROW;
                const int r   = s % NROW;
                int grow = y0 - MD + r;        // clamped (dead rows get sc=0)
                grow = grow < 0 ? 0 : (grow > H_ - 1 ? H_ - 1 : grow);
                const float* src =
                    t2 + (((size_t)(b * C_ + c0 + ch2)) * H_ + grow) * W_ + jsrc * 4;
                __builtin_amdgcn_global_load_lds(
                    (const __attribute__((address_space(1))) unsigned int*)src,
                    (__attribute__((address_space(3))) unsigned int*)&t2s[buf][ch2][r][0],
                    16, 0, 0);
            }
        }
    };

    STAGE(0, 0);
    __syncthreads();                            // phase 0 staged

    for (int ph = 0; ph < NPH; ++ph) {
        const int buf = ph & 1;
        if (ph + 1 < NPH) STAGE(buf ^ 1, ph + 1);   // in flight under compute

        const int c0 = ph * CHK;
        #pragma unroll
        for (int ch = 0; ch < CHK; ++ch) {
            // t1 from global (L1-cached, 9-wave reuse)
            const float* pc1 = p1 + (size_t)(c0 + ch) * chstr;
            const float4v a0 = *(const float4v*)(pc1);
            const float4v a1 = *(const float4v*)(pc1 + 4);

            // t2 window from LDS (swizzled, bank-uniform b128 reads)
            const char* row =
                (const char*)&t2s[buf][ch][0][0] + r_lds * (W_ * 4);
            float4v wl = *(const float4v*)(row + o0);
            const float4v v0 = *(const float4v*)(row + o1);
            const float4v v1 = *(const float4v*)(row + o2);
            float4v wr = *(const float4v*)(row + o3);
            #pragma unroll
            for (int q = 0; q < 4; ++q) {
                wl[q] = lm ? 0.0f : wl[q];
                wr[q] = rm ? 0.0f : wr[q];
            }

            float win[XPT + 2 * MD];
            #pragma unroll
            for (int q = 0; q < 4; ++q) {
                win[q]      = wl[q];
                win[4 + q]  = v0[q];
                win[8 + q]  = v1[q];
                win[12 + q] = wr[q];
            }

            #pragma unroll
            for (int dx = 0; dx < ND; ++dx)
                #pragma unroll
                for (int j = 0; j < XPT; ++j) {
                    const float aj = (j < 4) ? a0[j] : a1[j - 4];
                    acc[dx][j] = fmaf(aj, win[dx + j], acc[dx][j]);
                }
        }
        __syncthreads();   // next phase staged; all waves done with buf
    }

    #pragma unroll
    for (int dx = 0; dx < ND; ++dx) {
        float4v o0, o1;
        #pragma unroll
        for (int j = 0; j < 4; ++j) {
            o0[j] = acc[dx][j]     * sc;
            o1[j] = acc[dx][4 + j] * sc;
        }
        const size_t oidx =
            (((size_t)(b * ND * ND) + w * ND + dx) * H_ + yrow) * W_ + x0;
        *(float4v*)&out[oidx]     = o0;
        *(float4v*)&out[oidx + 4] = o1;
    }
}

extern "C" void kernel_launch(void* const* d_in, const int* in_sizes, int n_in,
                              void* d_out, int out_size, void* d_ws, size_t ws_size,
                              hipStream_t stream) {
    const float* t1 = (const float*)d_in[0];
    const float* t2 = (const float*)d_in[1];
    float* out      = (float*)d_out;
    corr_kernel<<<dim3(B_ * H_ / 2), NW * 64, 0, stream>>>(t1, t2, out);
}